// Round 1
// baseline (660.897 us; speedup 1.0000x reference)
//
#include <hip/hip_runtime.h>

typedef __attribute__((ext_vector_type(8))) short bf16x8;
typedef __attribute__((ext_vector_type(4))) float f32x4;

// ---------- helpers ----------
__device__ __forceinline__ unsigned short bf16_rne(float x){
  unsigned int u = __float_as_uint(x);
  unsigned int r = (u + 0x7FFFu + ((u >> 16) & 1u)) >> 16;
  return (unsigned short)r;
}
__device__ __forceinline__ float bf16_tof(unsigned short h){
  return __uint_as_float(((unsigned int)h) << 16);
}
__device__ __forceinline__ void split2(float x, unsigned short &hi, unsigned short &lo){
  hi = bf16_rne(x);
  lo = bf16_rne(x - bf16_tof(hi));
}
__device__ __forceinline__ void gload_lds16(const void* g, void* l){
  __builtin_amdgcn_global_load_lds((const __attribute__((address_space(1))) void*)g,
                                   (__attribute__((address_space(3))) void*)l, 16, 0, 0);
}

// K-index remap for the 3-term split expressed as a K=3072 concat GEMM.
// MAP 0: identity. MAP 1: blocks [c0|c1|c0] of a 2048-wide buffer.
// MAP 2: blocks [c0|c0|c1] of a 2048-wide buffer.
template<int MAP>
__device__ __forceinline__ int kmap(int k){
  if (MAP == 1) return (k < 2048) ? k : (k - 2048);
  if (MAP == 2) return (k < 1024) ? k : (k - 1024);
  return k;
}

// ---------- m97-style GEMM core: C[128x128] = sum_k A[128,kmapA(k)] * B[128,kmapB(k)]
// A: row-major [rows][lda], k-major.  B: "B^T form" row-major [cols][ldb], k-major.
template<int MAPA, int MAPB>
__device__ __forceinline__ void gemm_core(const unsigned short* __restrict__ A, int lda,
                                          const unsigned short* __restrict__ B, int ldb,
                                          int Kv,
                                          unsigned short* lsA, unsigned short* lsB,
                                          f32x4 acc[4][4])
{
  const int tid  = threadIdx.x;
  const int lane = tid & 63;
  const int w    = tid >> 6;
  const int wr   = (w >> 1) * 64;
  const int wc   = (w & 1) * 64;
  const int l15  = lane & 15;
  const int lg   = lane >> 4;

  f32x4 zero = {0.f, 0.f, 0.f, 0.f};
#pragma unroll
  for (int m = 0; m < 4; m++)
#pragma unroll
    for (int n = 0; n < 4; n++)
      acc[m][n] = zero;

  const int srow = tid >> 3;          // staging row (chunk i adds i*32)
  const int skk  = (tid & 7) << 3;    // staging k offset (8 bf16 = 16B per lane)

  for (int kt = 0; kt < Kv; kt += 64){
    const int ka = kmap<MAPA>(kt) + skk;
    const int kb = kmap<MAPB>(kt) + skk;
    __syncthreads();
#pragma unroll
    for (int i = 0; i < 4; i++){
      const int row = i * 32 + srow;
      gload_lds16(A + (size_t)row * lda + ka, lsA + i * 2048 + w * 512);
      gload_lds16(B + (size_t)row * ldb + kb, lsB + i * 2048 + w * 512);
    }
    __syncthreads();
#pragma unroll
    for (int s2 = 0; s2 < 2; s2++){
      bf16x8 af[4], bfr[4];
#pragma unroll
      for (int m = 0; m < 4; m++)
        af[m] = *(const bf16x8*)(lsA + (wr + m * 16 + l15) * 64 + s2 * 32 + lg * 8);
#pragma unroll
      for (int n = 0; n < 4; n++)
        bfr[n] = *(const bf16x8*)(lsB + (wc + n * 16 + l15) * 64 + s2 * 32 + lg * 8);
#pragma unroll
      for (int m = 0; m < 4; m++)
#pragma unroll
        for (int n = 0; n < 4; n++)
          acc[m][n] = __builtin_amdgcn_mfma_f32_16x16x32_bf16(af[m], bfr[n], acc[m][n], 0, 0, 0);
    }
  }
}

// ---------- small prep kernels ----------

// split a 1024-col fp32 matrix row into [hi | lo] bf16 (dst stride 2048). grid = rows.
__global__ __launch_bounds__(256) void k_split(const float* __restrict__ src,
                                               unsigned short* __restrict__ dst){
  const int row = blockIdx.x;
  const int c = threadIdx.x * 4;
  float4 val = *(const float4*)(src + (size_t)row * 1024 + c);
  ushort4 h, l;
  split2(val.x, h.x, l.x); split2(val.y, h.y, l.y);
  split2(val.z, h.z, l.z); split2(val.w, h.w, l.w);
  *(ushort4*)(dst + (size_t)row * 2048 + c) = h;
  *(ushort4*)(dst + (size_t)row * 2048 + 1024 + c) = l;
}

// split + transpose: dstT[col][row]=hi, dstT[col][1024+row]=lo (dstT stride 2048). grid = rows.
__global__ __launch_bounds__(256) void k_splitT(const float* __restrict__ src,
                                                unsigned short* __restrict__ dstT){
  const int row = blockIdx.x;
  const int c0 = threadIdx.x * 4;
  float4 val = *(const float4*)(src + (size_t)row * 1024 + c0);
  float vv[4] = {val.x, val.y, val.z, val.w};
#pragma unroll
  for (int i = 0; i < 4; i++){
    unsigned short h, l; split2(vv[i], h, l);
    dstT[(size_t)(c0 + i) * 2048 + row] = h;
    dstT[(size_t)(c0 + i) * 2048 + 1024 + row] = l;
  }
}

// wv[f] = sum_a Wb[f,a] * ba[a].  grid=256, 4 rows/block (one wave each).
__global__ __launch_bounds__(256) void k_wv(const float* __restrict__ Wb,
                                            const float* __restrict__ ba,
                                            float* __restrict__ wv){
  const int row = blockIdx.x * 4 + (threadIdx.x >> 6);
  const int lane = threadIdx.x & 63;
  float s = 0.f;
#pragma unroll
  for (int j = 0; j < 4; j++){
    const int c = lane * 4 + j * 256;
    float4 wb = *(const float4*)(Wb + (size_t)row * 1024 + c);
    float4 bb = *(const float4*)(ba + c);
    s += wb.x * bb.x + wb.y * bb.y + wb.z * bb.z + wb.w * bb.w;
  }
  for (int o = 32; o; o >>= 1) s += __shfl_xor(s, o);
  if (lane == 0) wv[row] = s;
}

// x split into x2=[hi|lo] plus v[row] = x[row,:] . wv.  grid = 32768 (one row/block).
__global__ __launch_bounds__(256) void k_split_x(const float* __restrict__ x,
                                                 unsigned short* __restrict__ x2,
                                                 const float* __restrict__ wv,
                                                 float* __restrict__ v){
  __shared__ float red[4];
  const int row = blockIdx.x;
  const int c = threadIdx.x * 4;
  float4 val = *(const float4*)(x + (size_t)row * 1024 + c);
  float4 wvv = *(const float4*)(wv + c);
  ushort4 h, l;
  split2(val.x, h.x, l.x); split2(val.y, h.y, l.y);
  split2(val.z, h.z, l.z); split2(val.w, h.w, l.w);
  *(ushort4*)(x2 + (size_t)row * 2048 + c) = h;
  *(ushort4*)(x2 + (size_t)row * 2048 + 1024 + c) = l;
  float s = val.x * wvv.x + val.y * wvv.y + val.z * wvv.z + val.w * wvv.w;
  for (int o = 32; o; o >>= 1) s += __shfl_xor(s, o);
  const int lane = threadIdx.x & 63, w = threadIdx.x >> 6;
  if (lane == 0) red[w] = s;
  __syncthreads();
  if (threadIdx.x == 0) v[row] = red[0] + red[1] + red[2] + red[3];
}

// ---------- GEMM instantiations ----------

// M = Wa*Wb^T with 3-term split; write M^T split: MT2[g][f]=hi, MT2[g][1024+f]=lo. grid 64.
__global__ __launch_bounds__(256) void k_gemm_mt(const unsigned short* __restrict__ Wa2,
                                                 const unsigned short* __restrict__ Wb2,
                                                 unsigned short* __restrict__ MT2){
  __shared__ __align__(16) unsigned short lsA[8192], lsB[8192];
  const int bm = blockIdx.x >> 3, bn = blockIdx.x & 7;
  f32x4 acc[4][4];
  gemm_core<1, 2>(Wa2 + (size_t)bm * 128 * 2048, 2048,
                  Wb2 + (size_t)bn * 128 * 2048, 2048, 3072, lsA, lsB, acc);
  const int tid = threadIdx.x, lane = tid & 63, w = tid >> 6;
  const int wr = (w >> 1) * 64, wc = (w & 1) * 64, l15 = lane & 15, lg = lane >> 4;
#pragma unroll
  for (int m = 0; m < 4; m++)
#pragma unroll
    for (int n = 0; n < 4; n++){
      const int g  = bn * 128 + wc + n * 16 + l15;
      const int f0 = bm * 128 + wr + m * 16 + lg * 4;
      ushort4 h4, l4;
      split2(acc[m][n][0], h4.x, l4.x); split2(acc[m][n][1], h4.y, l4.y);
      split2(acc[m][n][2], h4.z, l4.z); split2(acc[m][n][3], h4.w, l4.w);
      *(ushort4*)(MT2 + (size_t)g * 2048 + f0) = h4;
      *(ushort4*)(MT2 + (size_t)g * 2048 + 1024 + f0) = l4;
    }
}

// y = x*M with 3-term split; write y2=[hi|lo] into d_out (stride 2048). grid 2048.
__global__ __launch_bounds__(256) void k_gemm_y(const unsigned short* __restrict__ X2,
                                                const unsigned short* __restrict__ MT2,
                                                unsigned short* __restrict__ Y2){
  __shared__ __align__(16) unsigned short lsA[8192], lsB[8192];
  const int bm = blockIdx.x >> 3, bn = blockIdx.x & 7;
  f32x4 acc[4][4];
  gemm_core<1, 2>(X2 + (size_t)bm * 128 * 2048, 2048,
                  MT2 + (size_t)bn * 128 * 2048, 2048, 3072, lsA, lsB, acc);
  const int tid = threadIdx.x, lane = tid & 63, w = tid >> 6;
  const int wr = (w >> 1) * 64, wc = (w & 1) * 64, l15 = lane & 15, lg = lane >> 4;
#pragma unroll
  for (int m = 0; m < 4; m++)
#pragma unroll
    for (int n = 0; n < 4; n++){
      const int col  = bn * 128 + wc + n * 16 + l15;
      const int row0 = bm * 128 + wr + m * 16 + lg * 4;
#pragma unroll
      for (int q = 0; q < 4; q++){
        unsigned short hi, lo; split2(acc[m][n][q], hi, lo);
        const size_t base = (size_t)(row0 + q) * 2048;
        Y2[base + col] = hi;
        Y2[base + 1024 + col] = lo;
      }
    }
}

// featsT = (x_hi * Wg_hi + bg)^T stored bf16 [a][token]. grid 2048.
__global__ __launch_bounds__(256) void k_gemm_featsT(const unsigned short* __restrict__ X2,
                                                     const unsigned short* __restrict__ WgT,
                                                     const float* __restrict__ bg,
                                                     unsigned short* __restrict__ FT){
  __shared__ __align__(16) unsigned short lsA[8192], lsB[8192];
  const int bm = blockIdx.x >> 3, bn = blockIdx.x & 7;
  f32x4 acc[4][4];
  gemm_core<0, 0>(X2 + (size_t)bm * 128 * 2048, 2048,
                  WgT + (size_t)bn * 128 * 2048, 2048, 1024, lsA, lsB, acc);
  const int tid = threadIdx.x, lane = tid & 63, w = tid >> 6;
  const int wr = (w >> 1) * 64, wc = (w & 1) * 64, l15 = lane & 15, lg = lane >> 4;
#pragma unroll
  for (int m = 0; m < 4; m++)
#pragma unroll
    for (int n = 0; n < 4; n++){
      const int a   = bn * 128 + wc + n * 16 + l15;
      const int tk0 = bm * 128 + wr + m * 16 + lg * 4;
      const float bgv = bg[a];
      ushort4 h4;
      h4.x = bf16_rne(acc[m][n][0] + bgv); h4.y = bf16_rne(acc[m][n][1] + bgv);
      h4.z = bf16_rne(acc[m][n][2] + bgv); h4.w = bf16_rne(acc[m][n][3] + bgv);
      *(ushort4*)(FT + (size_t)a * 32768 + tk0) = h4;
    }
}

// per-frame scores = y_t * x_t^T (3-term split), fp32. grid 256 (one frame/block).
__global__ __launch_bounds__(256) void k_gemm_scores(const unsigned short* __restrict__ Y2,
                                                     const unsigned short* __restrict__ X2,
                                                     float* __restrict__ scores){
  __shared__ __align__(16) unsigned short lsA[8192], lsB[8192];
  const int t = blockIdx.x;
  f32x4 acc[4][4];
  gemm_core<2, 1>(Y2 + (size_t)t * 128 * 2048, 2048,
                  X2 + (size_t)t * 128 * 2048, 2048, 3072, lsA, lsB, acc);
  float* out = scores + (size_t)t * 16384;
  const int tid = threadIdx.x, lane = tid & 63, w = tid >> 6;
  const int wr = (w >> 1) * 64, wc = (w & 1) * 64, l15 = lane & 15, lg = lane >> 4;
#pragma unroll
  for (int m = 0; m < 4; m++)
#pragma unroll
    for (int n = 0; n < 4; n++){
      const int col  = wc + n * 16 + l15;
      const int row0 = wr + m * 16 + lg * 4;
#pragma unroll
      for (int q = 0; q < 4; q++)
        out[(size_t)(row0 + q) * 128 + col] = acc[m][n][q];
    }
}

// softmax over j with +v[t*128+j]; write bf16 weights. grid 8192 (4 rows/block, wave/row).
__global__ __launch_bounds__(256) void k_softmax(const float* __restrict__ scores,
                                                 const float* __restrict__ v,
                                                 unsigned short* __restrict__ wout){
  const int r = blockIdx.x * 4 + (threadIdx.x >> 6);
  const int lane = threadIdx.x & 63;
  const int t = r >> 7;
  const float* srow = scores + (size_t)r * 128;
  const float* vrow = v + (size_t)t * 128;
  float a = srow[lane] + vrow[lane];
  float b = srow[lane + 64] + vrow[lane + 64];
  float mx = fmaxf(a, b);
  for (int o = 32; o; o >>= 1) mx = fmaxf(mx, __shfl_xor(mx, o));
  float ea = __expf(a - mx), eb = __expf(b - mx);
  float s = ea + eb;
  for (int o = 32; o; o >>= 1) s += __shfl_xor(s, o);
  const float inv = 1.0f / s;
  wout[(size_t)r * 128 + lane] = bf16_rne(ea * inv);
  wout[(size_t)r * 128 + 64 + lane] = bf16_rne(eb * inv);
}

// out^T per frame: outT[f][s] = sum_j featsT[f][t*128+j] * w[s][j]; store out[t*128+s][f]. grid 2048.
__global__ __launch_bounds__(256) void k_gemm_out(const unsigned short* __restrict__ FT,
                                                  const unsigned short* __restrict__ Wt,
                                                  float* __restrict__ outp){
  __shared__ __align__(16) unsigned short lsA[8192], lsB[8192];
  const int t = blockIdx.x >> 3, fb = blockIdx.x & 7;
  f32x4 acc[4][4];
  gemm_core<0, 0>(FT + (size_t)fb * 128 * 32768 + (size_t)t * 128, 32768,
                  Wt + (size_t)t * 16384, 128, 128, lsA, lsB, acc);
  const int tid = threadIdx.x, lane = tid & 63, w = tid >> 6;
  const int wr = (w >> 1) * 64, wc = (w & 1) * 64, l15 = lane & 15, lg = lane >> 4;
#pragma unroll
  for (int m = 0; m < 4; m++)
#pragma unroll
    for (int n = 0; n < 4; n++){
      const int s  = wc + n * 16 + l15;
      const int f0 = fb * 128 + wr + m * 16 + lg * 4;
      *(f32x4*)(outp + ((size_t)t * 128 + s) * 1024 + f0) = acc[m][n];
    }
}

// ---------- launcher ----------
extern "C" void kernel_launch(void* const* d_in, const int* in_sizes, int n_in,
                              void* d_out, int out_size, void* d_ws, size_t ws_size,
                              hipStream_t stream) {
  const float* x  = (const float*)d_in[0];
  const float* Wa = (const float*)d_in[2];
  const float* ba = (const float*)d_in[3];
  const float* Wb = (const float*)d_in[4];
  const float* Wg = (const float*)d_in[6];
  const float* bg = (const float*)d_in[7];

  unsigned short* x2  = (unsigned short*)d_ws;            // 32768 x 2048
  unsigned short* Wa2 = x2 + (size_t)32768 * 2048;        // 1024 x 2048
  unsigned short* Wb2 = Wa2 + (size_t)1024 * 2048;        // 1024 x 2048
  unsigned short* WgT = Wb2 + (size_t)1024 * 2048;        // 1024 x 2048 (transposed split)
  unsigned short* MT2 = WgT + (size_t)1024 * 2048;        // 1024 x 2048 (M^T split)
  unsigned short* FT  = MT2 + (size_t)1024 * 2048;        // 1024 x 32768 (featsT bf16)
  float* scores = (float*)(FT + (size_t)1024 * 32768);    // 256*128*128 fp32
  unsigned short* wts = (unsigned short*)(scores + (size_t)256 * 128 * 128); // bf16
  float* wv = (float*)(wts + (size_t)256 * 128 * 128);    // 1024
  float* v  = wv + 1024;                                  // 32768
  size_t need = (size_t)((char*)(v + 32768) - (char*)d_ws);
  if (ws_size < need) return;

  unsigned short* y2 = (unsigned short*)d_out;            // y hi/lo lives in d_out until PV

  k_split   <<<1024,  256, 0, stream>>>(Wa, Wa2);
  k_split   <<<1024,  256, 0, stream>>>(Wb, Wb2);
  k_splitT  <<<1024,  256, 0, stream>>>(Wg, WgT);
  k_wv      <<<256,   256, 0, stream>>>(Wb, ba, wv);
  k_split_x <<<32768, 256, 0, stream>>>(x, x2, wv, v);
  k_gemm_mt <<<64,    256, 0, stream>>>(Wa2, Wb2, MT2);
  k_gemm_featsT<<<2048, 256, 0, stream>>>(x2, WgT, bg, FT);
  k_gemm_y  <<<2048,  256, 0, stream>>>(x2, MT2, y2);
  k_gemm_scores<<<256, 256, 0, stream>>>(y2, x2, scores);
  k_softmax <<<8192,  256, 0, stream>>>(scores, v, wts);
  k_gemm_out<<<2048,  256, 0, stream>>>(FT, wts, (float*)d_out);
}

// Round 2
// 587.029 us; speedup vs baseline: 1.1258x; 1.1258x over previous
//
#include <hip/hip_runtime.h>

typedef __attribute__((ext_vector_type(8))) short bf16x8;
typedef __attribute__((ext_vector_type(4))) float f32x4;

// ---------- helpers ----------
__device__ __forceinline__ unsigned short bf16_rne(float x){
  unsigned int u = __float_as_uint(x);
  unsigned int r = (u + 0x7FFFu + ((u >> 16) & 1u)) >> 16;
  return (unsigned short)r;
}
__device__ __forceinline__ float bf16_tof(unsigned short h){
  return __uint_as_float(((unsigned int)h) << 16);
}
__device__ __forceinline__ void split2(float x, unsigned short &hi, unsigned short &lo){
  hi = bf16_rne(x);
  lo = bf16_rne(x - bf16_tof(hi));
}
__device__ __forceinline__ void gload_lds16(const void* g, void* l){
  __builtin_amdgcn_global_load_lds((const __attribute__((address_space(1))) void*)g,
                                   (__attribute__((address_space(3))) void*)l, 16, 0, 0);
}

// K-index remap for the 3-term split expressed as a K=3072 concat GEMM.
// MAP 0: identity. MAP 1: blocks [hi|lo|hi]. MAP 2: blocks [hi|hi|lo].
template<int MAP>
__device__ __forceinline__ int kmap(int k){
  if (MAP == 1) return (k < 2048) ? k : (k - 2048);
  if (MAP == 2) return (k < 1024) ? k : (k - 1024);
  return k;
}

// ============================================================================
// Pipelined 256x256 GEMM, BK=32, 512 threads (8 waves, 2x4), depth-3 prefetch,
// 4 LDS slots x 32KB, counted vmcnt(8), XOR-swizzled LDS (2-way max = free).
// A: row-major [M][2048] k-major. B: B^T-form row-major [N][2048] k-major.
// EPI 0: split hi/lo write to outp stride 2048 (y path).
// EPI 1: bf16(acc+bias[col]) transposed write: outp[col*32768 + row] (featsT).
// ============================================================================
template<int MAPA, int MAPB, int NK, int EPI>
__global__ __launch_bounds__(512, 2) void k_gemm256(
    const unsigned short* __restrict__ A, const unsigned short* __restrict__ B,
    unsigned short* __restrict__ outp, const float* __restrict__ bias)
{
  __shared__ __align__(16) unsigned short lds_u[65536];   // 128 KiB
  char* ldsb = (char*)lds_u;

  // XCD-aware bid swizzle (gridDim.x == 512, divisible by 8)
  int bid = blockIdx.x;
  bid = (bid & 7) * 64 + (bid >> 3);
  const int bm = bid >> 2, bn = bid & 3;

  const int tid  = threadIdx.x;
  const int w    = tid >> 6;
  const int lane = tid & 63;
  const int wm   = w >> 2;          // 0..1
  const int wn   = w & 3;           // 0..3
  const int l15  = lane & 15;
  const int lg   = lane >> 4;       // k-octet 0..3

  // ---- staging source map (inverse swizzle), 2 loads per 16KB sub-tile ----
  // chunk o16 = j*512 + tid ; p = o16>>3 ; s = o16&7 ; q = s ^ (p&7)
  // row = 2p + (q>>2) ; koct = q&3 ; src = base[row][koct*8 .. +8)
  int srow[2], slg[2];
#pragma unroll
  for (int j = 0; j < 2; j++){
    int o16 = j * 512 + tid;
    int p = o16 >> 3, s = o16 & 7;
    int q = s ^ (p & 7);
    srow[j] = 2 * p + (q >> 2);
    slg[j]  = q & 3;
  }
  const unsigned short* aS0 = A + (size_t)(bm * 256 + srow[0]) * 2048 + slg[0] * 8;
  const unsigned short* aS1 = A + (size_t)(bm * 256 + srow[1]) * 2048 + slg[1] * 8;
  const unsigned short* bS0 = B + (size_t)(bn * 256 + srow[0]) * 2048 + slg[0] * 8;
  const unsigned short* bS1 = B + (size_t)(bn * 256 + srow[1]) * 2048 + slg[1] * 8;

  // ---- swizzled ds_read offsets (s is constant across m/n: p&7 == (l15>>1)&7) ----
  const int sA   = (((l15 & 1) << 2) | lg) ^ ((l15 >> 1) & 7);
  const int aOff = wm * 8192 + (l15 >> 1) * 128 + sA * 16;            // + m*1024
  const int bOff = 16384 + wn * 4096 + (l15 >> 1) * 128 + sA * 16;    // + n*1024

  f32x4 acc[8][4];
  f32x4 zero = {0.f, 0.f, 0.f, 0.f};
#pragma unroll
  for (int m = 0; m < 8; m++)
#pragma unroll
    for (int n = 0; n < 4; n++) acc[m][n] = zero;

  auto STAGE = [&](int t){
    char* base = ldsb + (size_t)(t & 3) * 32768;
    const int ka = kmap<MAPA>(t * 32);
    const int kb = kmap<MAPB>(t * 32);
    gload_lds16(aS0 + ka, base + w * 1024);
    gload_lds16(aS1 + ka, base + 8192 + w * 1024);
    gload_lds16(bS0 + kb, base + 16384 + w * 1024);
    gload_lds16(bS1 + kb, base + 16384 + 8192 + w * 1024);
  };

  STAGE(0); STAGE(1); STAGE(2);
  asm volatile("s_waitcnt vmcnt(8)" ::: "memory");   // tile 0 landed; 2 tiles in flight
  __builtin_amdgcn_s_barrier();
  __builtin_amdgcn_sched_barrier(0);

  for (int t = 0; t < NK; t++){
    if (t + 3 < NK) STAGE(t + 3);
    const char* sb = ldsb + (size_t)(t & 3) * 32768;
    bf16x8 af[8], bfr[4];
#pragma unroll
    for (int m = 0; m < 8; m++) af[m]  = *(const bf16x8*)(sb + aOff + m * 1024);
#pragma unroll
    for (int n = 0; n < 4; n++) bfr[n] = *(const bf16x8*)(sb + bOff + n * 1024);
    __builtin_amdgcn_s_setprio(1);
#pragma unroll
    for (int m = 0; m < 8; m++)
#pragma unroll
      for (int n = 0; n < 4; n++)
        acc[m][n] = __builtin_amdgcn_mfma_f32_16x16x32_bf16(af[m], bfr[n], acc[m][n], 0, 0, 0);
    __builtin_amdgcn_s_setprio(0);
    const int rem = NK - t - 2;   // tiles beyond t+1 whose loads may stay in flight
    if (rem >= 2)      asm volatile("s_waitcnt vmcnt(8)" ::: "memory");
    else if (rem == 1) asm volatile("s_waitcnt vmcnt(4)" ::: "memory");
    else               asm volatile("s_waitcnt vmcnt(0)" ::: "memory");
    __builtin_amdgcn_s_barrier();
    __builtin_amdgcn_sched_barrier(0);
  }

#pragma unroll
  for (int m = 0; m < 8; m++)
#pragma unroll
    for (int n = 0; n < 4; n++){
      const int col  = bn * 256 + wn * 64 + n * 16 + l15;
      const int row0 = bm * 256 + wm * 128 + m * 16 + lg * 4;
      if (EPI == 0){
#pragma unroll
        for (int q = 0; q < 4; q++){
          unsigned short hi, lo; split2(acc[m][n][q], hi, lo);
          const size_t base = (size_t)(row0 + q) * 2048;
          outp[base + col] = hi;
          outp[base + 1024 + col] = lo;
        }
      } else {
        const float bgv = bias[col];
        ushort4 h4;
        h4.x = bf16_rne(acc[m][n][0] + bgv); h4.y = bf16_rne(acc[m][n][1] + bgv);
        h4.z = bf16_rne(acc[m][n][2] + bgv); h4.w = bf16_rne(acc[m][n][3] + bgv);
        *(ushort4*)(outp + (size_t)col * 32768 + row0) = h4;
      }
    }
}

// ============================================================================
// Pipelined per-frame scores: 2 frames/block, 512 threads. Per frame-half:
// 4 waves (2x2), wave tile 64x64. A=Y2 (MAP2), B=X2 (MAP1), K=3072, fp32 out.
// LDS slot 32KB = [Yf0 8K | Xf0 8K | Yf1 8K | Xf1 8K]; 4 slots; depth-3.
// ============================================================================
__global__ __launch_bounds__(512, 2) void k_scores2(
    const unsigned short* __restrict__ Y2, const unsigned short* __restrict__ X2,
    float* __restrict__ scores)
{
  __shared__ __align__(16) unsigned short lds_u[65536];   // 128 KiB
  char* ldsb = (char*)lds_u;

  const int f0 = blockIdx.x * 2;
  const int tid  = threadIdx.x;
  const int w    = tid >> 6;
  const int lane = tid & 63;
  const int fh   = w >> 2;          // frame half 0..1
  const int wq   = w & 3;
  const int wm   = wq >> 1, wn = wq & 1;
  const int l15  = lane & 15;
  const int lg   = lane >> 4;

  // staging source map: one gload per 8KB sub-tile; chunk = tid
  const int p0 = tid >> 3, s0 = tid & 7;
  const int q0 = s0 ^ (p0 & 7);
  const int srow = 2 * p0 + (q0 >> 2);
  const int slg  = q0 & 3;
  const unsigned short* yS0 = Y2 + (size_t)((f0    ) * 128 + srow) * 2048 + slg * 8;
  const unsigned short* xS0 = X2 + (size_t)((f0    ) * 128 + srow) * 2048 + slg * 8;
  const unsigned short* yS1 = Y2 + (size_t)((f0 + 1) * 128 + srow) * 2048 + slg * 8;
  const unsigned short* xS1 = X2 + (size_t)((f0 + 1) * 128 + srow) * 2048 + slg * 8;

  const int sA   = (((l15 & 1) << 2) | lg) ^ ((l15 >> 1) & 7);
  const int aOff = fh * 16384 +        wm * 4096 + (l15 >> 1) * 128 + sA * 16;  // + m*1024
  const int bOff = fh * 16384 + 8192 + wn * 4096 + (l15 >> 1) * 128 + sA * 16;  // + n*1024

  f32x4 acc[4][4];
  f32x4 zero = {0.f, 0.f, 0.f, 0.f};
#pragma unroll
  for (int m = 0; m < 4; m++)
#pragma unroll
    for (int n = 0; n < 4; n++) acc[m][n] = zero;

  auto STAGE = [&](int t){
    char* base = ldsb + (size_t)(t & 3) * 32768;
    const int ka = kmap<2>(t * 32);
    const int kb = kmap<1>(t * 32);
    gload_lds16(yS0 + ka, base +         w * 1024);
    gload_lds16(xS0 + kb, base +  8192 + w * 1024);
    gload_lds16(yS1 + ka, base + 16384 + w * 1024);
    gload_lds16(xS1 + kb, base + 24576 + w * 1024);
  };

  const int NK = 96;
  STAGE(0); STAGE(1); STAGE(2);
  asm volatile("s_waitcnt vmcnt(8)" ::: "memory");
  __builtin_amdgcn_s_barrier();
  __builtin_amdgcn_sched_barrier(0);

  for (int t = 0; t < NK; t++){
    if (t + 3 < NK) STAGE(t + 3);
    const char* sb = ldsb + (size_t)(t & 3) * 32768;
    bf16x8 af[4], bfr[4];
#pragma unroll
    for (int m = 0; m < 4; m++) af[m]  = *(const bf16x8*)(sb + aOff + m * 1024);
#pragma unroll
    for (int n = 0; n < 4; n++) bfr[n] = *(const bf16x8*)(sb + bOff + n * 1024);
    __builtin_amdgcn_s_setprio(1);
#pragma unroll
    for (int m = 0; m < 4; m++)
#pragma unroll
      for (int n = 0; n < 4; n++)
        acc[m][n] = __builtin_amdgcn_mfma_f32_16x16x32_bf16(af[m], bfr[n], acc[m][n], 0, 0, 0);
    __builtin_amdgcn_s_setprio(0);
    const int rem = NK - t - 2;
    if (rem >= 2)      asm volatile("s_waitcnt vmcnt(8)" ::: "memory");
    else if (rem == 1) asm volatile("s_waitcnt vmcnt(4)" ::: "memory");
    else               asm volatile("s_waitcnt vmcnt(0)" ::: "memory");
    __builtin_amdgcn_s_barrier();
    __builtin_amdgcn_sched_barrier(0);
  }

  float* out = scores + (size_t)(f0 + fh) * 16384;
#pragma unroll
  for (int m = 0; m < 4; m++)
#pragma unroll
    for (int n = 0; n < 4; n++){
      const int col  = wn * 64 + n * 16 + l15;
      const int row0 = wm * 64 + m * 16 + lg * 4;
#pragma unroll
      for (int q = 0; q < 4; q++)
        out[(size_t)(row0 + q) * 128 + col] = acc[m][n][q];
    }
}

// ============================================================================
// Old m97-style core, kept for the small GEMMs (mt: 64 blocks, out: K=128).
// ============================================================================
template<int MAPA, int MAPB>
__device__ __forceinline__ void gemm_core(const unsigned short* __restrict__ A, int lda,
                                          const unsigned short* __restrict__ B, int ldb,
                                          int Kv,
                                          unsigned short* lsA, unsigned short* lsB,
                                          f32x4 acc[4][4])
{
  const int tid  = threadIdx.x;
  const int lane = tid & 63;
  const int w    = tid >> 6;
  const int wr   = (w >> 1) * 64;
  const int wc   = (w & 1) * 64;
  const int l15  = lane & 15;
  const int lg   = lane >> 4;

  f32x4 zero = {0.f, 0.f, 0.f, 0.f};
#pragma unroll
  for (int m = 0; m < 4; m++)
#pragma unroll
    for (int n = 0; n < 4; n++)
      acc[m][n] = zero;

  const int srow = tid >> 3;
  const int skk  = (tid & 7) << 3;

  for (int kt = 0; kt < Kv; kt += 64){
    const int ka = kmap<MAPA>(kt) + skk;
    const int kb = kmap<MAPB>(kt) + skk;
    __syncthreads();
#pragma unroll
    for (int i = 0; i < 4; i++){
      const int row = i * 32 + srow;
      gload_lds16(A + (size_t)row * lda + ka, lsA + i * 2048 + w * 512);
      gload_lds16(B + (size_t)row * ldb + kb, lsB + i * 2048 + w * 512);
    }
    __syncthreads();
#pragma unroll
    for (int s2 = 0; s2 < 2; s2++){
      bf16x8 af[4], bfr[4];
#pragma unroll
      for (int m = 0; m < 4; m++)
        af[m] = *(const bf16x8*)(lsA + (wr + m * 16 + l15) * 64 + s2 * 32 + lg * 8);
#pragma unroll
      for (int n = 0; n < 4; n++)
        bfr[n] = *(const bf16x8*)(lsB + (wc + n * 16 + l15) * 64 + s2 * 32 + lg * 8);
#pragma unroll
      for (int m = 0; m < 4; m++)
#pragma unroll
        for (int n = 0; n < 4; n++)
          acc[m][n] = __builtin_amdgcn_mfma_f32_16x16x32_bf16(af[m], bfr[n], acc[m][n], 0, 0, 0);
    }
  }
}

// ---------- small prep kernels ----------
__global__ __launch_bounds__(256) void k_split(const float* __restrict__ src,
                                               unsigned short* __restrict__ dst){
  const int row = blockIdx.x;
  const int c = threadIdx.x * 4;
  float4 val = *(const float4*)(src + (size_t)row * 1024 + c);
  ushort4 h, l;
  split2(val.x, h.x, l.x); split2(val.y, h.y, l.y);
  split2(val.z, h.z, l.z); split2(val.w, h.w, l.w);
  *(ushort4*)(dst + (size_t)row * 2048 + c) = h;
  *(ushort4*)(dst + (size_t)row * 2048 + 1024 + c) = l;
}

__global__ __launch_bounds__(256) void k_splitT(const float* __restrict__ src,
                                                unsigned short* __restrict__ dstT){
  const int row = blockIdx.x;
  const int c0 = threadIdx.x * 4;
  float4 val = *(const float4*)(src + (size_t)row * 1024 + c0);
  float vv[4] = {val.x, val.y, val.z, val.w};
#pragma unroll
  for (int i = 0; i < 4; i++){
    unsigned short h, l; split2(vv[i], h, l);
    dstT[(size_t)(c0 + i) * 2048 + row] = h;
    dstT[(size_t)(c0 + i) * 2048 + 1024 + row] = l;
  }
}

__global__ __launch_bounds__(256) void k_wv(const float* __restrict__ Wb,
                                            const float* __restrict__ ba,
                                            float* __restrict__ wv){
  const int row = blockIdx.x * 4 + (threadIdx.x >> 6);
  const int lane = threadIdx.x & 63;
  float s = 0.f;
#pragma unroll
  for (int j = 0; j < 4; j++){
    const int c = lane * 4 + j * 256;
    float4 wb = *(const float4*)(Wb + (size_t)row * 1024 + c);
    float4 bb = *(const float4*)(ba + c);
    s += wb.x * bb.x + wb.y * bb.y + wb.z * bb.z + wb.w * bb.w;
  }
  for (int o = 32; o; o >>= 1) s += __shfl_xor(s, o);
  if (lane == 0) wv[row] = s;
}

// x split + v dot: one wave per row, 4 rows/block, grid-stride. grid 2048.
__global__ __launch_bounds__(256) void k_split_x(const float* __restrict__ x,
                                                 unsigned short* __restrict__ x2,
                                                 const float* __restrict__ wv,
                                                 float* __restrict__ v){
  const int w = threadIdx.x >> 6, lane = threadIdx.x & 63;
#pragma unroll
  for (int it = 0; it < 4; it++){
    const int row = blockIdx.x * 4 + w + it * 8192;
    float s = 0.f;
#pragma unroll
    for (int j = 0; j < 4; j++){
      const int c = lane * 4 + j * 256;
      float4 val = *(const float4*)(x + (size_t)row * 1024 + c);
      float4 wvv = *(const float4*)(wv + c);
      ushort4 h, l;
      split2(val.x, h.x, l.x); split2(val.y, h.y, l.y);
      split2(val.z, h.z, l.z); split2(val.w, h.w, l.w);
      *(ushort4*)(x2 + (size_t)row * 2048 + c) = h;
      *(ushort4*)(x2 + (size_t)row * 2048 + 1024 + c) = l;
      s += val.x * wvv.x + val.y * wvv.y + val.z * wvv.z + val.w * wvv.w;
    }
    for (int o = 32; o; o >>= 1) s += __shfl_xor(s, o);
    if (lane == 0) v[row] = s;
  }
}

// M = Wa*Wb^T 3-term split; write M^T split. grid 64.
__global__ __launch_bounds__(256) void k_gemm_mt(const unsigned short* __restrict__ Wa2,
                                                 const unsigned short* __restrict__ Wb2,
                                                 unsigned short* __restrict__ MT2){
  __shared__ __align__(16) unsigned short lsA[8192], lsB[8192];
  const int bm = blockIdx.x >> 3, bn = blockIdx.x & 7;
  f32x4 acc[4][4];
  gemm_core<1, 2>(Wa2 + (size_t)bm * 128 * 2048, 2048,
                  Wb2 + (size_t)bn * 128 * 2048, 2048, 3072, lsA, lsB, acc);
  const int tid = threadIdx.x, lane = tid & 63, w = tid >> 6;
  const int wr = (w >> 1) * 64, wc = (w & 1) * 64, l15 = lane & 15, lg = lane >> 4;
#pragma unroll
  for (int m = 0; m < 4; m++)
#pragma unroll
    for (int n = 0; n < 4; n++){
      const int g  = bn * 128 + wc + n * 16 + l15;
      const int f0 = bm * 128 + wr + m * 16 + lg * 4;
      ushort4 h4, l4;
      split2(acc[m][n][0], h4.x, l4.x); split2(acc[m][n][1], h4.y, l4.y);
      split2(acc[m][n][2], h4.z, l4.z); split2(acc[m][n][3], h4.w, l4.w);
      *(ushort4*)(MT2 + (size_t)g * 2048 + f0) = h4;
      *(ushort4*)(MT2 + (size_t)g * 2048 + 1024 + f0) = l4;
    }
}

// softmax over j with +v[t*128+j]; write bf16 weights. grid 8192.
__global__ __launch_bounds__(256) void k_softmax(const float* __restrict__ scores,
                                                 const float* __restrict__ v,
                                                 unsigned short* __restrict__ wout){
  const int r = blockIdx.x * 4 + (threadIdx.x >> 6);
  const int lane = threadIdx.x & 63;
  const int t = r >> 7;
  const float* srow = scores + (size_t)r * 128;
  const float* vrow = v + (size_t)t * 128;
  float a = srow[lane] + vrow[lane];
  float b = srow[lane + 64] + vrow[lane + 64];
  float mx = fmaxf(a, b);
  for (int o = 32; o; o >>= 1) mx = fmaxf(mx, __shfl_xor(mx, o));
  float ea = __expf(a - mx), eb = __expf(b - mx);
  float s = ea + eb;
  for (int o = 32; o; o >>= 1) s += __shfl_xor(s, o);
  const float inv = 1.0f / s;
  wout[(size_t)r * 128 + lane] = bf16_rne(ea * inv);
  wout[(size_t)r * 128 + 64 + lane] = bf16_rne(eb * inv);
}

// out per frame via featsT: grid 2048.
__global__ __launch_bounds__(256) void k_gemm_out(const unsigned short* __restrict__ FT,
                                                  const unsigned short* __restrict__ Wt,
                                                  float* __restrict__ outp){
  __shared__ __align__(16) unsigned short lsA[8192], lsB[8192];
  const int t = blockIdx.x >> 3, fb = blockIdx.x & 7;
  f32x4 acc[4][4];
  gemm_core<0, 0>(FT + (size_t)fb * 128 * 32768 + (size_t)t * 128, 32768,
                  Wt + (size_t)t * 16384, 128, 128, lsA, lsB, acc);
  const int tid = threadIdx.x, lane = tid & 63, w = tid >> 6;
  const int wr = (w >> 1) * 64, wc = (w & 1) * 64, l15 = lane & 15, lg = lane >> 4;
#pragma unroll
  for (int m = 0; m < 4; m++)
#pragma unroll
    for (int n = 0; n < 4; n++){
      const int s  = wc + n * 16 + l15;
      const int f0 = fb * 128 + wr + m * 16 + lg * 4;
      *(f32x4*)(outp + ((size_t)t * 128 + s) * 1024 + f0) = acc[m][n];
    }
}

// ---------- launcher ----------
extern "C" void kernel_launch(void* const* d_in, const int* in_sizes, int n_in,
                              void* d_out, int out_size, void* d_ws, size_t ws_size,
                              hipStream_t stream) {
  const float* x  = (const float*)d_in[0];
  const float* Wa = (const float*)d_in[2];
  const float* ba = (const float*)d_in[3];
  const float* Wb = (const float*)d_in[4];
  const float* Wg = (const float*)d_in[6];
  const float* bg = (const float*)d_in[7];

  unsigned short* x2  = (unsigned short*)d_ws;            // 32768 x 2048
  unsigned short* Wa2 = x2 + (size_t)32768 * 2048;        // 1024 x 2048
  unsigned short* Wb2 = Wa2 + (size_t)1024 * 2048;        // 1024 x 2048
  unsigned short* WgT = Wb2 + (size_t)1024 * 2048;        // 1024 x 2048
  unsigned short* MT2 = WgT + (size_t)1024 * 2048;        // 1024 x 2048
  unsigned short* FT  = MT2 + (size_t)1024 * 2048;        // 1024 x 32768
  float* scores = (float*)(FT + (size_t)1024 * 32768);    // 256*128*128 fp32
  unsigned short* wts = (unsigned short*)(scores + (size_t)256 * 128 * 128);
  float* wv = (float*)(wts + (size_t)256 * 128 * 128);    // 1024
  float* v  = wv + 1024;                                  // 32768
  size_t need = (size_t)((char*)(v + 32768) - (char*)d_ws);
  if (ws_size < need) return;

  unsigned short* y2 = (unsigned short*)d_out;            // y hi/lo in d_out until PV

  k_split   <<<1024, 256, 0, stream>>>(Wa, Wa2);
  k_split   <<<1024, 256, 0, stream>>>(Wb, Wb2);
  k_splitT  <<<1024, 256, 0, stream>>>(Wg, WgT);
  k_wv      <<<256,  256, 0, stream>>>(Wb, ba, wv);
  k_split_x <<<2048, 256, 0, stream>>>(x, x2, wv, v);
  k_gemm_mt <<<64,   256, 0, stream>>>(Wa2, Wb2, MT2);
  k_gemm256<0, 0, 32, 1><<<512, 512, 0, stream>>>(x2, WgT, FT, bg);      // featsT
  k_gemm256<1, 2, 96, 0><<<512, 512, 0, stream>>>(x2, MT2, y2, nullptr); // y = x*M
  k_scores2 <<<128,  512, 0, stream>>>(y2, x2, scores);
  k_softmax <<<8192, 256, 0, stream>>>(scores, v, wts);
  k_gemm_out<<<2048, 256, 0, stream>>>(FT, wts, (float*)d_out);
}

// Round 3
// 581.121 us; speedup vs baseline: 1.1373x; 1.0102x over previous
//
#include <hip/hip_runtime.h>

typedef __attribute__((ext_vector_type(8))) short bf16x8;
typedef __attribute__((ext_vector_type(4))) float f32x4;

// ---------- helpers ----------
__device__ __forceinline__ unsigned short bf16_rne(float x){
  unsigned int u = __float_as_uint(x);
  unsigned int r = (u + 0x7FFFu + ((u >> 16) & 1u)) >> 16;
  return (unsigned short)r;
}
__device__ __forceinline__ float bf16_tof(unsigned short h){
  return __uint_as_float(((unsigned int)h) << 16);
}
__device__ __forceinline__ void split2(float x, unsigned short &hi, unsigned short &lo){
  hi = bf16_rne(x);
  lo = bf16_rne(x - bf16_tof(hi));
}
__device__ __forceinline__ void gload_lds16(const void* g, void* l){
  __builtin_amdgcn_global_load_lds((const __attribute__((address_space(1))) void*)g,
                                   (__attribute__((address_space(3))) void*)l, 16, 0, 0);
}

// K-index remap for the 3-term split expressed as a K=3072 concat GEMM.
// MAP 0: identity. MAP 1: blocks [hi|lo|hi]. MAP 2: blocks [hi|hi|lo].
template<int MAP>
__device__ __forceinline__ int kmap(int k){
  if (MAP == 1) return (k < 2048) ? k : (k - 2048);
  if (MAP == 2) return (k < 1024) ? k : (k - 1024);
  return k;
}

// ============================================================================
// Pipelined 256x256 GEMM, BK=32, 512 threads (8 waves, 2x4), depth-3 LDS
// prefetch (4 slots x 32KB), REGISTER double-buffered fragments with counted
// lgkmcnt(12) so ds_read latency hides under MFMA. vmcnt counted (never 0 in
// steady state). XOR-swizzled LDS (bank-conflict-free, verified R2: 0).
// A: row-major [M][2048] k-major. B: B^T-form row-major [N][2048] k-major.
// EPI 0: split hi/lo write to outp stride 2048 (y path).
// EPI 1: bf16(acc+bias[col]) transposed write: outp[col*32768 + row] (featsT).
// ============================================================================
template<int MAPA, int MAPB, int NK, int EPI>
__global__ __launch_bounds__(512, 2) void k_gemm256(
    const unsigned short* __restrict__ A, const unsigned short* __restrict__ B,
    unsigned short* __restrict__ outp, const float* __restrict__ bias)
{
  __shared__ __align__(16) unsigned short lds_u[65536];   // 128 KiB
  char* ldsb = (char*)lds_u;

  // XCD-aware bid swizzle (gridDim.x == 512, divisible by 8)
  int bid = blockIdx.x;
  bid = (bid & 7) * 64 + (bid >> 3);
  const int bm = bid >> 2, bn = bid & 3;

  const int tid  = threadIdx.x;
  const int w    = tid >> 6;
  const int lane = tid & 63;
  const int wm   = w >> 2;          // 0..1
  const int wn   = w & 3;           // 0..3
  const int l15  = lane & 15;
  const int lg   = lane >> 4;       // k-octet 0..3

  // ---- staging source map (inverse swizzle), 2 loads per 16KB sub-tile ----
  int srow[2], slg[2];
#pragma unroll
  for (int j = 0; j < 2; j++){
    int o16 = j * 512 + tid;
    int p = o16 >> 3, s = o16 & 7;
    int q = s ^ (p & 7);
    srow[j] = 2 * p + (q >> 2);
    slg[j]  = q & 3;
  }
  const unsigned short* aS0 = A + (size_t)(bm * 256 + srow[0]) * 2048 + slg[0] * 8;
  const unsigned short* aS1 = A + (size_t)(bm * 256 + srow[1]) * 2048 + slg[1] * 8;
  const unsigned short* bS0 = B + (size_t)(bn * 256 + srow[0]) * 2048 + slg[0] * 8;
  const unsigned short* bS1 = B + (size_t)(bn * 256 + srow[1]) * 2048 + slg[1] * 8;

  // ---- swizzled ds_read offsets ----
  const int sA   = (((l15 & 1) << 2) | lg) ^ ((l15 >> 1) & 7);
  const int aOff = wm * 8192 + (l15 >> 1) * 128 + sA * 16;            // + m*1024
  const int bOff = 16384 + wn * 4096 + (l15 >> 1) * 128 + sA * 16;    // + n*1024

  f32x4 acc[8][4];
  f32x4 zero = {0.f, 0.f, 0.f, 0.f};
#pragma unroll
  for (int m = 0; m < 8; m++)
#pragma unroll
    for (int n = 0; n < 4; n++) acc[m][n] = zero;

  auto STAGE = [&](int t){
    char* base = ldsb + (size_t)(t & 3) * 32768;
    const int ka = kmap<MAPA>(t * 32);
    const int kb = kmap<MAPB>(t * 32);
    gload_lds16(aS0 + ka, base + w * 1024);
    gload_lds16(aS1 + ka, base + 8192 + w * 1024);
    gload_lds16(bS0 + kb, base + 16384 + w * 1024);
    gload_lds16(bS1 + kb, base + 16384 + 8192 + w * 1024);
  };
  auto LOADF = [&](bf16x8 (&fa)[8], bf16x8 (&fb)[4], int t){
    const char* sb = ldsb + (size_t)(t & 3) * 32768;
#pragma unroll
    for (int m = 0; m < 8; m++) fa[m] = *(const bf16x8*)(sb + aOff + m * 1024);
#pragma unroll
    for (int n = 0; n < 4; n++) fb[n] = *(const bf16x8*)(sb + bOff + n * 1024);
  };
  auto MFMA32 = [&](bf16x8 (&fa)[8], bf16x8 (&fb)[4]){
    __builtin_amdgcn_s_setprio(1);
#pragma unroll
    for (int m = 0; m < 8; m++)
#pragma unroll
      for (int n = 0; n < 4; n++)
        acc[m][n] = __builtin_amdgcn_mfma_f32_16x16x32_bf16(fa[m], fb[n], acc[m][n], 0, 0, 0);
    __builtin_amdgcn_s_setprio(0);
  };

  bf16x8 a0[8], b0[4], a1[8], b1[4];

  STAGE(0); STAGE(1); STAGE(2);
  asm volatile("s_waitcnt vmcnt(8)" ::: "memory");   // tile 0 landed
  __builtin_amdgcn_s_barrier();
  __builtin_amdgcn_sched_barrier(0);
  LOADF(a0, b0, 0);

#pragma unroll 1
  for (int t = 0; t < NK; t += 2){
    // ---- sub-iter A: compute tile t, prefetch frags of t+1 ----
    if (t + 2 < NK) asm volatile("s_waitcnt vmcnt(4)" ::: "memory");  // t+1 landed
    else            asm volatile("s_waitcnt vmcnt(0)" ::: "memory");
    __builtin_amdgcn_s_barrier();
    __builtin_amdgcn_sched_barrier(0);
    if (t + 3 < NK) STAGE(t + 3);
    LOADF(a1, b1, t + 1);
    asm volatile("s_waitcnt lgkmcnt(12)" ::: "memory");               // tile t frags ready
    __builtin_amdgcn_sched_barrier(0);
    MFMA32(a0, b0);
    // ---- sub-iter B: compute tile t+1, prefetch frags of t+2 ----
    if (t + 3 < NK) asm volatile("s_waitcnt vmcnt(4)" ::: "memory");  // t+2 landed
    else            asm volatile("s_waitcnt vmcnt(0)" ::: "memory");
    __builtin_amdgcn_s_barrier();
    __builtin_amdgcn_sched_barrier(0);
    if (t + 4 < NK) STAGE(t + 4);
    if (t + 2 < NK){
      LOADF(a0, b0, t + 2);
      asm volatile("s_waitcnt lgkmcnt(12)" ::: "memory");
    } else {
      asm volatile("s_waitcnt lgkmcnt(0)" ::: "memory");
    }
    __builtin_amdgcn_sched_barrier(0);
    MFMA32(a1, b1);
  }

#pragma unroll
  for (int m = 0; m < 8; m++)
#pragma unroll
    for (int n = 0; n < 4; n++){
      const int col  = bn * 256 + wn * 64 + n * 16 + l15;
      const int row0 = bm * 256 + wm * 128 + m * 16 + lg * 4;
      if (EPI == 0){
#pragma unroll
        for (int q = 0; q < 4; q++){
          unsigned short hi, lo; split2(acc[m][n][q], hi, lo);
          const size_t base = (size_t)(row0 + q) * 2048;
          outp[base + col] = hi;
          outp[base + 1024 + col] = lo;
        }
      } else {
        const float bgv = bias[col];
        ushort4 h4;
        h4.x = bf16_rne(acc[m][n][0] + bgv); h4.y = bf16_rne(acc[m][n][1] + bgv);
        h4.z = bf16_rne(acc[m][n][2] + bgv); h4.w = bf16_rne(acc[m][n][3] + bgv);
        *(ushort4*)(outp + (size_t)col * 32768 + row0) = h4;
      }
    }
}

// ============================================================================
// Pipelined per-frame scores + FUSED softmax: 2 frames/block, 512 threads.
// Per frame-half: 4 waves (2x2), wave tile 64x64. A=Y2 (MAP2), B=X2 (MAP1),
// K=3072. Reg-dbuf frags, counted lgkmcnt(8). Epilogue: acc -> LDS fp32
// (rotation swizzle), per-row wave softmax (+v), bf16 weights out.
// ============================================================================
__global__ __launch_bounds__(512, 2) void k_scores2(
    const unsigned short* __restrict__ Y2, const unsigned short* __restrict__ X2,
    const float* __restrict__ v, unsigned short* __restrict__ wout)
{
  __shared__ __align__(16) unsigned short lds_u[65536];   // 128 KiB
  char* ldsb = (char*)lds_u;

  const int f0 = blockIdx.x * 2;
  const int tid  = threadIdx.x;
  const int w    = tid >> 6;
  const int lane = tid & 63;
  const int fh   = w >> 2;          // frame half 0..1
  const int wq   = w & 3;
  const int wm   = wq >> 1, wn = wq & 1;
  const int l15  = lane & 15;
  const int lg   = lane >> 4;

  const int p0 = tid >> 3, s0 = tid & 7;
  const int q0 = s0 ^ (p0 & 7);
  const int srow = 2 * p0 + (q0 >> 2);
  const int slg  = q0 & 3;
  const unsigned short* yS0 = Y2 + (size_t)((f0    ) * 128 + srow) * 2048 + slg * 8;
  const unsigned short* xS0 = X2 + (size_t)((f0    ) * 128 + srow) * 2048 + slg * 8;
  const unsigned short* yS1 = Y2 + (size_t)((f0 + 1) * 128 + srow) * 2048 + slg * 8;
  const unsigned short* xS1 = X2 + (size_t)((f0 + 1) * 128 + srow) * 2048 + slg * 8;

  const int sA   = (((l15 & 1) << 2) | lg) ^ ((l15 >> 1) & 7);
  const int aOff = fh * 16384 +        wm * 4096 + (l15 >> 1) * 128 + sA * 16;  // + m*1024
  const int bOff = fh * 16384 + 8192 + wn * 4096 + (l15 >> 1) * 128 + sA * 16;  // + n*1024

  f32x4 acc[4][4];
  f32x4 zero = {0.f, 0.f, 0.f, 0.f};
#pragma unroll
  for (int m = 0; m < 4; m++)
#pragma unroll
    for (int n = 0; n < 4; n++) acc[m][n] = zero;

  auto STAGE = [&](int t){
    char* base = ldsb + (size_t)(t & 3) * 32768;
    const int ka = kmap<2>(t * 32);
    const int kb = kmap<1>(t * 32);
    gload_lds16(yS0 + ka, base +         w * 1024);
    gload_lds16(xS0 + kb, base +  8192 + w * 1024);
    gload_lds16(yS1 + ka, base + 16384 + w * 1024);
    gload_lds16(xS1 + kb, base + 24576 + w * 1024);
  };
  auto LOADF = [&](bf16x8 (&fa)[4], bf16x8 (&fb)[4], int t){
    const char* sb = ldsb + (size_t)(t & 3) * 32768;
#pragma unroll
    for (int m = 0; m < 4; m++) fa[m] = *(const bf16x8*)(sb + aOff + m * 1024);
#pragma unroll
    for (int n = 0; n < 4; n++) fb[n] = *(const bf16x8*)(sb + bOff + n * 1024);
  };
  auto MFMA16 = [&](bf16x8 (&fa)[4], bf16x8 (&fb)[4]){
    __builtin_amdgcn_s_setprio(1);
#pragma unroll
    for (int m = 0; m < 4; m++)
#pragma unroll
      for (int n = 0; n < 4; n++)
        acc[m][n] = __builtin_amdgcn_mfma_f32_16x16x32_bf16(fa[m], fb[n], acc[m][n], 0, 0, 0);
    __builtin_amdgcn_s_setprio(0);
  };

  bf16x8 fa0[4], fb0[4], fa1[4], fb1[4];
  const int NK = 96;

  STAGE(0); STAGE(1); STAGE(2);
  asm volatile("s_waitcnt vmcnt(8)" ::: "memory");
  __builtin_amdgcn_s_barrier();
  __builtin_amdgcn_sched_barrier(0);
  LOADF(fa0, fb0, 0);

#pragma unroll 1
  for (int t = 0; t < NK; t += 2){
    if (t + 2 < NK) asm volatile("s_waitcnt vmcnt(4)" ::: "memory");
    else            asm volatile("s_waitcnt vmcnt(0)" ::: "memory");
    __builtin_amdgcn_s_barrier();
    __builtin_amdgcn_sched_barrier(0);
    if (t + 3 < NK) STAGE(t + 3);
    LOADF(fa1, fb1, t + 1);
    asm volatile("s_waitcnt lgkmcnt(8)" ::: "memory");
    __builtin_amdgcn_sched_barrier(0);
    MFMA16(fa0, fb0);
    if (t + 3 < NK) asm volatile("s_waitcnt vmcnt(4)" ::: "memory");
    else            asm volatile("s_waitcnt vmcnt(0)" ::: "memory");
    __builtin_amdgcn_s_barrier();
    __builtin_amdgcn_sched_barrier(0);
    if (t + 4 < NK) STAGE(t + 4);
    if (t + 2 < NK){
      LOADF(fa0, fb0, t + 2);
      asm volatile("s_waitcnt lgkmcnt(8)" ::: "memory");
    } else {
      asm volatile("s_waitcnt lgkmcnt(0)" ::: "memory");
    }
    __builtin_amdgcn_sched_barrier(0);
    MFMA16(fa1, fb1);
  }

  // ---- fused softmax: acc -> LDS fp32 (rotation swizzle), reduce, bf16 out ----
  __builtin_amdgcn_s_barrier();                 // all K-loop LDS reads retired
  float* sf = (float*)ldsb;                     // 2 x 64KB fp32 frames
#pragma unroll
  for (int m = 0; m < 4; m++)
#pragma unroll
    for (int n = 0; n < 4; n++){
      const int col = wn * 64 + n * 16 + l15;
#pragma unroll
      for (int q = 0; q < 4; q++){
        const int row = wm * 64 + m * 16 + lg * 4 + q;
        sf[fh * 16384 + row * 128 + ((col + (row & 31) * 4) & 127)] = acc[m][n][q];
      }
    }
  __syncthreads();
#pragma unroll 1
  for (int i = 0; i < 32; i++){
    const int rr  = w * 32 + i;                 // 0..255
    const int fhh = rr >> 7, row = rr & 127;
    const float* rp = sf + fhh * 16384 + row * 128;
    const float* vr = v + (size_t)(f0 + fhh) * 128;
    const int rot = (row & 31) * 4;
    float a = rp[(lane + rot) & 127]      + vr[lane];
    float b = rp[(lane + 64 + rot) & 127] + vr[lane + 64];
    float mx = fmaxf(a, b);
    for (int o = 32; o; o >>= 1) mx = fmaxf(mx, __shfl_xor(mx, o));
    float ea = __expf(a - mx), eb = __expf(b - mx);
    float s = ea + eb;
    for (int o = 32; o; o >>= 1) s += __shfl_xor(s, o);
    const float inv = 1.0f / s;
    unsigned short* wrow = wout + ((size_t)(f0 + fhh) * 128 + row) * 128;
    wrow[lane]      = bf16_rne(ea * inv);
    wrow[lane + 64] = bf16_rne(eb * inv);
  }
}

// ============================================================================
// m97-style core for the small GEMMs (mt: 64 blocks; out: K=128).
// ============================================================================
template<int MAPA, int MAPB>
__device__ __forceinline__ void gemm_core(const unsigned short* __restrict__ A, int lda,
                                          const unsigned short* __restrict__ B, int ldb,
                                          int Kv,
                                          unsigned short* lsA, unsigned short* lsB,
                                          f32x4 acc[4][4])
{
  const int tid  = threadIdx.x;
  const int lane = tid & 63;
  const int w    = tid >> 6;
  const int wr   = (w >> 1) * 64;
  const int wc   = (w & 1) * 64;
  const int l15  = lane & 15;
  const int lg   = lane >> 4;

  f32x4 zero = {0.f, 0.f, 0.f, 0.f};
#pragma unroll
  for (int m = 0; m < 4; m++)
#pragma unroll
    for (int n = 0; n < 4; n++)
      acc[m][n] = zero;

  const int srow = tid >> 3;
  const int skk  = (tid & 7) << 3;

  for (int kt = 0; kt < Kv; kt += 64){
    const int ka = kmap<MAPA>(kt) + skk;
    const int kb = kmap<MAPB>(kt) + skk;
    __syncthreads();
#pragma unroll
    for (int i = 0; i < 4; i++){
      const int row = i * 32 + srow;
      gload_lds16(A + (size_t)row * lda + ka, lsA + i * 2048 + w * 512);
      gload_lds16(B + (size_t)row * ldb + kb, lsB + i * 2048 + w * 512);
    }
    __syncthreads();
#pragma unroll
    for (int s2 = 0; s2 < 2; s2++){
      bf16x8 af[4], bfr[4];
#pragma unroll
      for (int m = 0; m < 4; m++)
        af[m] = *(const bf16x8*)(lsA + (wr + m * 16 + l15) * 64 + s2 * 32 + lg * 8);
#pragma unroll
      for (int n = 0; n < 4; n++)
        bfr[n] = *(const bf16x8*)(lsB + (wc + n * 16 + l15) * 64 + s2 * 32 + lg * 8);
#pragma unroll
      for (int m = 0; m < 4; m++)
#pragma unroll
        for (int n = 0; n < 4; n++)
          acc[m][n] = __builtin_amdgcn_mfma_f32_16x16x32_bf16(af[m], bfr[n], acc[m][n], 0, 0, 0);
    }
  }
}

// ---------- small prep kernels ----------
__global__ __launch_bounds__(256) void k_split(const float* __restrict__ src,
                                               unsigned short* __restrict__ dst){
  const int row = blockIdx.x;
  const int c = threadIdx.x * 4;
  float4 val = *(const float4*)(src + (size_t)row * 1024 + c);
  ushort4 h, l;
  split2(val.x, h.x, l.x); split2(val.y, h.y, l.y);
  split2(val.z, h.z, l.z); split2(val.w, h.w, l.w);
  *(ushort4*)(dst + (size_t)row * 2048 + c) = h;
  *(ushort4*)(dst + (size_t)row * 2048 + 1024 + c) = l;
}

__global__ __launch_bounds__(256) void k_splitT(const float* __restrict__ src,
                                                unsigned short* __restrict__ dstT){
  const int row = blockIdx.x;
  const int c0 = threadIdx.x * 4;
  float4 val = *(const float4*)(src + (size_t)row * 1024 + c0);
  float vv[4] = {val.x, val.y, val.z, val.w};
#pragma unroll
  for (int i = 0; i < 4; i++){
    unsigned short h, l; split2(vv[i], h, l);
    dstT[(size_t)(c0 + i) * 2048 + row] = h;
    dstT[(size_t)(c0 + i) * 2048 + 1024 + row] = l;
  }
}

__global__ __launch_bounds__(256) void k_wv(const float* __restrict__ Wb,
                                            const float* __restrict__ ba,
                                            float* __restrict__ wv){
  const int row = blockIdx.x * 4 + (threadIdx.x >> 6);
  const int lane = threadIdx.x & 63;
  float s = 0.f;
#pragma unroll
  for (int j = 0; j < 4; j++){
    const int c = lane * 4 + j * 256;
    float4 wb = *(const float4*)(Wb + (size_t)row * 1024 + c);
    float4 bb = *(const float4*)(ba + c);
    s += wb.x * bb.x + wb.y * bb.y + wb.z * bb.z + wb.w * bb.w;
  }
  for (int o = 32; o; o >>= 1) s += __shfl_xor(s, o);
  if (lane == 0) wv[row] = s;
}

// x split + v dot: one wave per row, 4 rows/block, grid-stride. grid 2048.
__global__ __launch_bounds__(256) void k_split_x(const float* __restrict__ x,
                                                 unsigned short* __restrict__ x2,
                                                 const float* __restrict__ wv,
                                                 float* __restrict__ v){
  const int w = threadIdx.x >> 6, lane = threadIdx.x & 63;
#pragma unroll
  for (int it = 0; it < 4; it++){
    const int row = blockIdx.x * 4 + w + it * 8192;
    float s = 0.f;
#pragma unroll
    for (int j = 0; j < 4; j++){
      const int c = lane * 4 + j * 256;
      float4 val = *(const float4*)(x + (size_t)row * 1024 + c);
      float4 wvv = *(const float4*)(wv + c);
      ushort4 h, l;
      split2(val.x, h.x, l.x); split2(val.y, h.y, l.y);
      split2(val.z, h.z, l.z); split2(val.w, h.w, l.w);
      *(ushort4*)(x2 + (size_t)row * 2048 + c) = h;
      *(ushort4*)(x2 + (size_t)row * 2048 + 1024 + c) = l;
      s += val.x * wvv.x + val.y * wvv.y + val.z * wvv.z + val.w * wvv.w;
    }
    for (int o = 32; o; o >>= 1) s += __shfl_xor(s, o);
    if (lane == 0) v[row] = s;
  }
}

// M = Wa*Wb^T 3-term split; write M^T split. grid 64.
__global__ __launch_bounds__(256) void k_gemm_mt(const unsigned short* __restrict__ Wa2,
                                                 const unsigned short* __restrict__ Wb2,
                                                 unsigned short* __restrict__ MT2){
  __shared__ __align__(16) unsigned short lsA[8192], lsB[8192];
  const int bm = blockIdx.x >> 3, bn = blockIdx.x & 7;
  f32x4 acc[4][4];
  gemm_core<1, 2>(Wa2 + (size_t)bm * 128 * 2048, 2048,
                  Wb2 + (size_t)bn * 128 * 2048, 2048, 3072, lsA, lsB, acc);
  const int tid = threadIdx.x, lane = tid & 63, w = tid >> 6;
  const int wr = (w >> 1) * 64, wc = (w & 1) * 64, l15 = lane & 15, lg = lane >> 4;
#pragma unroll
  for (int m = 0; m < 4; m++)
#pragma unroll
    for (int n = 0; n < 4; n++){
      const int g  = bn * 128 + wc + n * 16 + l15;
      const int f0 = bm * 128 + wr + m * 16 + lg * 4;
      ushort4 h4, l4;
      split2(acc[m][n][0], h4.x, l4.x); split2(acc[m][n][1], h4.y, l4.y);
      split2(acc[m][n][2], h4.z, l4.z); split2(acc[m][n][3], h4.w, l4.w);
      *(ushort4*)(MT2 + (size_t)g * 2048 + f0) = h4;
      *(ushort4*)(MT2 + (size_t)g * 2048 + 1024 + f0) = l4;
    }
}

// out per frame via featsT: grid 2048.
__global__ __launch_bounds__(256) void k_gemm_out(const unsigned short* __restrict__ FT,
                                                  const unsigned short* __restrict__ Wt,
                                                  float* __restrict__ outp){
  __shared__ __align__(16) unsigned short lsA[8192], lsB[8192];
  const int t = blockIdx.x >> 3, fb = blockIdx.x & 7;
  f32x4 acc[4][4];
  gemm_core<0, 0>(FT + (size_t)fb * 128 * 32768 + (size_t)t * 128, 32768,
                  Wt + (size_t)t * 16384, 128, 128, lsA, lsB, acc);
  const int tid = threadIdx.x, lane = tid & 63, w = tid >> 6;
  const int wr = (w >> 1) * 64, wc = (w & 1) * 64, l15 = lane & 15, lg = lane >> 4;
#pragma unroll
  for (int m = 0; m < 4; m++)
#pragma unroll
    for (int n = 0; n < 4; n++){
      const int s  = wc + n * 16 + l15;
      const int f0 = fb * 128 + wr + m * 16 + lg * 4;
      *(f32x4*)(outp + ((size_t)t * 128 + s) * 1024 + f0) = acc[m][n];
    }
}

// ---------- launcher ----------
extern "C" void kernel_launch(void* const* d_in, const int* in_sizes, int n_in,
                              void* d_out, int out_size, void* d_ws, size_t ws_size,
                              hipStream_t stream) {
  const float* x  = (const float*)d_in[0];
  const float* Wa = (const float*)d_in[2];
  const float* ba = (const float*)d_in[3];
  const float* Wb = (const float*)d_in[4];
  const float* Wg = (const float*)d_in[6];
  const float* bg = (const float*)d_in[7];

  unsigned short* x2  = (unsigned short*)d_ws;            // 32768 x 2048
  unsigned short* Wa2 = x2 + (size_t)32768 * 2048;        // 1024 x 2048
  unsigned short* Wb2 = Wa2 + (size_t)1024 * 2048;        // 1024 x 2048
  unsigned short* WgT = Wb2 + (size_t)1024 * 2048;        // 1024 x 2048
  unsigned short* MT2 = WgT + (size_t)1024 * 2048;        // 1024 x 2048
  unsigned short* FT  = MT2 + (size_t)1024 * 2048;        // 1024 x 32768
  float* scores = (float*)(FT + (size_t)1024 * 32768);    // (unused now, kept for layout)
  unsigned short* wts = (unsigned short*)(scores + (size_t)256 * 128 * 128);
  float* wv = (float*)(wts + (size_t)256 * 128 * 128);    // 1024
  float* v  = wv + 1024;                                  // 32768
  size_t need = (size_t)((char*)(v + 32768) - (char*)d_ws);
  if (ws_size < need) return;

  unsigned short* y2 = (unsigned short*)d_out;            // y hi/lo in d_out until PV

  k_split   <<<1024, 256, 0, stream>>>(Wa, Wa2);
  k_split   <<<1024, 256, 0, stream>>>(Wb, Wb2);
  k_splitT  <<<1024, 256, 0, stream>>>(Wg, WgT);
  k_wv      <<<256,  256, 0, stream>>>(Wb, ba, wv);
  k_split_x <<<2048, 256, 0, stream>>>(x, x2, wv, v);
  k_gemm_mt <<<64,   256, 0, stream>>>(Wa2, Wb2, MT2);
  k_gemm256<0, 0, 32, 1><<<512, 512, 0, stream>>>(x2, WgT, FT, bg);      // featsT
  k_gemm256<1, 2, 96, 0><<<512, 512, 0, stream>>>(x2, MT2, y2, nullptr); // y = x*M
  k_scores2 <<<128,  512, 0, stream>>>(y2, x2, v, wts);
  k_gemm_out<<<2048, 256, 0, stream>>>(FT, wts, (float*)d_out);
}